// Round 26
// baseline (115.026 us; speedup 1.0000x reference)
//
#include <hip/hip_runtime.h>
#include <hip/hip_bf16.h>

#define B_   32
#define L_   2048
#define CIN  256
#define HID  512
#define TL   32
#define TPT  8                     // tiles per block = 256 rows
#define NGRP 256                   // 256-row groups
#define NBLK (NGRP * 4)            // x4 col-quarters = 1024 blocks

// 2*log2(e): baked into Wc/bc so the gemm output feeds exp2 directly.
#define TANH_SCALE 2.885390081777927

typedef __bf16 bf16_t;
typedef __bf16 bf16x8 __attribute__((ext_vector_type(8)));
typedef __bf16 bf16x4 __attribute__((ext_vector_type(4)));
typedef float  f32x4  __attribute__((ext_vector_type(4)));

// LDS map (80 KB -> exactly 2 blocks/CU):
//   A dbuf @0:      buf*32768 + pipe*16384 + row*512 (swizzled rows, 32 rows)
//   TY dbuf @65536: buf*8192 + wq*2048 + ri*1024 + cj*512 + l15*32 + l4*8
#define APIPE  16384u
#define ABUF   32768u
#define TY_OFF 65536u

// ---------------------------------------------------------------------------
// Kernel 1: compose Wc = TANH_SCALE * (W2 @ W1) (fp32 -> bf16),
//           bc = TANH_SCALE * (W2 @ b1 + b2).   (R21-proven shape)
// ---------------------------------------------------------------------------
__global__ void compose_kernel(const float* __restrict__ W1, const float* __restrict__ W2,
                               const float* __restrict__ b1, const float* __restrict__ b2,
                               bf16_t* __restrict__ Wc, float* __restrict__ bc)
{
    const int g = blockIdx.x;            // 512
    const int c = threadIdx.x;           // 256
    const float* w2row = W2 + (size_t)g * HID;
    float s[8] = {0.f, 0.f, 0.f, 0.f, 0.f, 0.f, 0.f, 0.f};
#pragma unroll 2
    for (int h = 0; h < HID; h += 8) {
#pragma unroll
        for (int k = 0; k < 8; ++k)
            s[k] = fmaf(w2row[h + k], W1[(size_t)(h + k) * CIN + c], s[k]);
    }
    float tot = ((s[0] + s[1]) + (s[2] + s[3])) + ((s[4] + s[5]) + (s[6] + s[7]));
    Wc[(size_t)g * CIN + c] = (bf16_t)(tot * (float)TANH_SCALE);
    if (c < 64) {                        // wave 0: parallel bc reduction
        float t = 0.f;
        for (int h = c; h < HID; h += 64)
            t = fmaf(w2row[h], b1[h], t);
#pragma unroll
        for (int off = 32; off >= 1; off >>= 1)
            t += __shfl_xor(t, off);
        if (c == 0) bc[g] = (t + b2[g]) * (float)TANH_SCALE;
    }
}

// ---------------------------------------------------------------------------
// Kernel 2: fused GEMM + tanh-pair-product + row-reduction, TL=32.
// The R25 budget analysis: W-refetch from L1/L2 was ~8 MB/CU (~52 us of L1
// fill) at TL=16 — the dominant floor term. TL=32 halves rows-per-W-read.
// Pipe-split keeps it feasible (R23's TL=32 without pipe-split spilled):
// wave = 32 cols x ONE pipe x 2 row-frags -> acc 16 (AGPR), 2 A-reads :
// 4 MFMA per kk. Staging reuses one v[4] in two rounds (E at tile top ->
// writeE mid-gemm; L mid-gemm -> writeL after tanh). launch_bounds (512,3)
// = spill cap ~170 (actual ~100 total -> 4 waves/SIMD tier at runtime).
// LDS 80 KB -> exactly 2 blocks/CU. XCD pairing, TY dbuf exchange,
// atomicAdd epilogue all R24-proven.
// Tripwires: WRITE_SIZE <1MB (spill); Occupancy ~45-50 (2 blocks).
// ---------------------------------------------------------------------------
__global__ __launch_bounds__(512, 3)
void fused_kernel(const float* __restrict__ x, const float* __restrict__ y,
                  const bf16_t* __restrict__ Wc, const float* __restrict__ bc,
                  float* __restrict__ out)
{
    __shared__ char U[81920];

    const int tid  = threadIdx.x;
    const int lane = tid & 63;
    const int wv   = tid >> 6;           // wave 0..7
    const int l15  = lane & 15;
    const int l4   = lane >> 4;

    // XCD-pairing decode: d%8 == grp%8 for all 4 q's of a grp (bijective)
    const int d    = blockIdx.x;
    const int grp  = (d & 7) + 8 * (d >> 5);
    const int q    = (d >> 3) & 3;

    const int pipe = wv >> 2;            // 0 = x-waves, 1 = y-waves
    const int wq   = wv & 3;
    const int gc0  = q * 128 + wq * 32;  // this wave's output-col base

    // bias fragments (scaled)
    f32x4 bcv[2];
#pragma unroll
    for (int cj = 0; cj < 2; ++cj) {
        float4 t4 = *reinterpret_cast<const float4*>(bc + gc0 + cj * 16 + l4 * 4);
        bcv[cj] = (f32x4){t4.x, t4.y, t4.z, t4.w};
    }

    // staging identity: threads 0-255 (x-waves) stage x, 256-511 stage y;
    // 8 thr/row over 32 rows; each thread 8 float4 in two v[4] rounds.
    const int sp   = tid >> 8;           // == pipe of this thread's wave
    const int t8   = tid & 255;
    const int srow = t8 >> 3;            // row 0..31
    const int sq   = t8 & 7;             // base float4 slot
    const unsigned sswz = (unsigned)((srow & 15) << 4);
    const unsigned soff = (unsigned)(sp * APIPE + srow * 512);
    const float* sptr = (sp ? y : x) + ((size_t)grp * (TPT * TL) + srow) * CIN;

    float4 v[4];
    auto loadE = [&](const float* rowbase) {
        const float4* s4 = reinterpret_cast<const float4*>(rowbase);
#pragma unroll
        for (int c = 0; c < 4; ++c) v[c] = s4[sq + 8 * c];
    };
    auto loadL = [&](const float* rowbase) {
        const float4* s4 = reinterpret_cast<const float4*>(rowbase);
#pragma unroll
        for (int c = 0; c < 4; ++c) v[c] = s4[sq + 8 * (c + 4)];
    };
    auto writeV = [&](int buf, int half) {
        char* p = U + (unsigned)(buf * ABUF) + soff;
#pragma unroll
        for (int c = 0; c < 4; ++c) {
            const int f = sq + 8 * (c + half * 4);
            bf16x4 h;
            h[0] = (bf16_t)v[c].x; h[1] = (bf16_t)v[c].y;
            h[2] = (bf16_t)v[c].z; h[3] = (bf16_t)v[c].w;
            *reinterpret_cast<bf16x4*>(p + (((unsigned)(8 * f)) ^ sswz)) = h;
        }
    };

    // A fragment bases [ri] (own pipe); per-kk addr = base ^ (kk<<6)
    unsigned abase[2];
#pragma unroll
    for (int ri = 0; ri < 2; ++ri)
        abase[ri] = (pipe ? APIPE : 0u) + (unsigned)((ri * 16 + l15) * 512) +
                    (((unsigned)(l4 * 16)) ^ ((unsigned)(l15 << 4)));
    // TY slot base (dbuf via +buf*8192)
    const unsigned tyb = TY_OFF + (unsigned)(wq * 2048 + l15 * 32 + l4 * 8);

    f32x4 psum[2];
    psum[0] = (f32x4){0.f, 0.f, 0.f, 0.f};
    psum[1] = (f32x4){0.f, 0.f, 0.f, 0.f};

    // prologue: stage tile 0 into buf 0 (two sequential v[4] rounds)
    loadE(sptr); writeV(0, 0);
    loadL(sptr); writeV(0, 1);
    __syncthreads();

    for (int t = 0; t < TPT; ++t) {
        const bool pf = (t + 1 < TPT);
        const int cur = t & 1;
        const float* nptr = sptr + TL * CIN;
        if (pf) loadE(nptr);             // E loads fly under gemm half 1

        f32x4 acc[2][2];                 // [ri][cj], 16 AGPR
#pragma unroll
        for (int ri = 0; ri < 2; ++ri)
#pragma unroll
            for (int cj = 0; cj < 2; ++cj) acc[ri][cj] = bcv[cj];

        const unsigned cb = (unsigned)(cur * ABUF);
        __builtin_amdgcn_s_setprio(1);
#pragma unroll
        for (int kk = 0; kk < 4; ++kk) { // gemm half 1
            bf16x8 w[2];
#pragma unroll
            for (int cj = 0; cj < 2; ++cj)
                w[cj] = *reinterpret_cast<const bf16x8*>(
                    Wc + (size_t)(gc0 + cj * 16 + l15) * CIN + kk * 32 + l4 * 8);
            const unsigned kx = (unsigned)(kk << 6);
            bf16x8 a0 = *reinterpret_cast<const bf16x8*>(U + cb + (abase[0] ^ kx));
            bf16x8 a1 = *reinterpret_cast<const bf16x8*>(U + cb + (abase[1] ^ kx));
#pragma unroll
            for (int cj = 0; cj < 2; ++cj) {
                acc[0][cj] = __builtin_amdgcn_mfma_f32_16x16x32_bf16(w[cj], a0, acc[0][cj], 0, 0, 0);
                acc[1][cj] = __builtin_amdgcn_mfma_f32_16x16x32_bf16(w[cj], a1, acc[1][cj], 0, 0, 0);
            }
        }
        __builtin_amdgcn_s_setprio(0);

        if (pf) {
            writeV(cur ^ 1, 0);          // E half into the idle buffer
            loadL(nptr);                 // L loads fly under gemm half 2
        }

        __builtin_amdgcn_s_setprio(1);
#pragma unroll
        for (int kk = 4; kk < 8; ++kk) { // gemm half 2
            bf16x8 w[2];
#pragma unroll
            for (int cj = 0; cj < 2; ++cj)
                w[cj] = *reinterpret_cast<const bf16x8*>(
                    Wc + (size_t)(gc0 + cj * 16 + l15) * CIN + kk * 32 + l4 * 8);
            const unsigned kx = (unsigned)(kk << 6);
            bf16x8 a0 = *reinterpret_cast<const bf16x8*>(U + cb + (abase[0] ^ kx));
            bf16x8 a1 = *reinterpret_cast<const bf16x8*>(U + cb + (abase[1] ^ kx));
#pragma unroll
            for (int cj = 0; cj < 2; ++cj) {
                acc[0][cj] = __builtin_amdgcn_mfma_f32_16x16x32_bf16(w[cj], a0, acc[0][cj], 0, 0, 0);
                acc[1][cj] = __builtin_amdgcn_mfma_f32_16x16x32_bf16(w[cj], a1, acc[1][cj], 0, 0, 0);
            }
        }
        __builtin_amdgcn_s_setprio(0);

        // ---- tanh own pipe (scale baked in): t = 1 - 2/(exp2(a)+1)
#pragma unroll
        for (int ri = 0; ri < 2; ++ri)
#pragma unroll
            for (int cj = 0; cj < 2; ++cj)
#pragma unroll
                for (int r2 = 0; r2 < 4; ++r2)
                    acc[ri][cj][r2] = fmaf(-2.0f,
                        __builtin_amdgcn_rcpf(exp2f(acc[ri][cj][r2]) + 1.0f), 1.0f);

        if (pipe) {                      // y-waves: publish tanh as bf16
#pragma unroll
            for (int ri = 0; ri < 2; ++ri)
#pragma unroll
                for (int cj = 0; cj < 2; ++cj) {
                    bf16x4 tv;
#pragma unroll
                    for (int r2 = 0; r2 < 4; ++r2) tv[r2] = (bf16_t)acc[ri][cj][r2];
                    *reinterpret_cast<bf16x4*>(
                        U + tyb + (unsigned)(cur * 8192 + ri * 1024 + cj * 512)) = tv;
                }
        }

        if (pf) writeV(cur ^ 1, 1);      // L half into the idle buffer

        __syncthreads();                 // publish TY[cur] + A[cur^1]

        if (!pipe) {                     // x-waves: product into psum
#pragma unroll
            for (int ri = 0; ri < 2; ++ri)
#pragma unroll
                for (int cj = 0; cj < 2; ++cj) {
                    bf16x4 o = *reinterpret_cast<const bf16x4*>(
                        U + tyb + (unsigned)(cur * 8192 + ri * 1024 + cj * 512));
#pragma unroll
                    for (int r2 = 0; r2 < 4; ++r2)
                        psum[cj][r2] = fmaf(acc[ri][cj][r2], (float)o[r2], psum[cj][r2]);
                }
        }
        sptr = nptr;
    }

    // x-waves: reduce over the 16 row-lanes, then atomicAdd into out
    if (!pipe) {
#pragma unroll
        for (int cj = 0; cj < 2; ++cj)
#pragma unroll
            for (int r2 = 0; r2 < 4; ++r2) {
                float s = psum[cj][r2];
                s += __shfl_xor(s, 1);
                s += __shfl_xor(s, 2);
                s += __shfl_xor(s, 4);
                s += __shfl_xor(s, 8);
                psum[cj][r2] = s;
            }
        if (l15 == 0) {
            const int b = grp >> 3;      // batch = grp/8
            float* ob = out + (size_t)b * HID + gc0 + l4 * 4;
#pragma unroll
            for (int cj = 0; cj < 2; ++cj)
#pragma unroll
                for (int r2 = 0; r2 < 4; ++r2)
                    atomicAdd(ob + cj * 16 + r2, psum[cj][r2]);
        }
    }
}

extern "C" void kernel_launch(void* const* d_in, const int* in_sizes, int n_in,
                              void* d_out, int out_size, void* d_ws, size_t ws_size,
                              hipStream_t stream)
{
    const float* x  = (const float*)d_in[0];
    const float* y  = (const float*)d_in[1];
    const float* W1 = (const float*)d_in[2];
    const float* b1 = (const float*)d_in[3];
    const float* W2 = (const float*)d_in[4];
    const float* b2 = (const float*)d_in[5];
    float* out = (float*)d_out;

    char* ws = (char*)d_ws;
    bf16_t* Wc = (bf16_t*)ws;                    // 256 KB
    float*  bc = (float*)(ws + (256 << 10));     // 2 KB

    hipMemsetAsync(out, 0, (size_t)out_size * sizeof(float), stream);
    hipLaunchKernelGGL(compose_kernel, dim3(HID), dim3(CIN), 0, stream, W1, W2, b1, b2, Wc, bc);
    hipLaunchKernelGGL(fused_kernel, dim3(NBLK), dim3(512), 0, stream, x, y, Wc, bc, out);
}